// Round 6
// baseline (358.626 us; speedup 1.0000x reference)
//
#include <hip/hip_runtime.h>

// Bipartite GATConv forward (both directions), fp32.
//   - CSR build: bucketed 2-phase (k_part -> k_build), single-writer lines
//     (R4-confirmed fix for cross-XCD partial-line write amplification).
//     k_part uses 4096-edge chunks (longer per-bucket bursts, less cross-XCD
//     line sharing); gCnt zeroing folded into k_fold (memset dispatch gone).
//   - k_gemm computes xs = relu(X)@W + a_s epilogue + a_d epilogue.
//   - k_agg: single-pass softmax (exact: exp(-max) cancels; logits ~N(0,1.4),
//     max ~9.5 << 88 so no overflow), half-wave-per-edge float4 gathers,
//     MASKED 4-chunk loop: clamped indices + zeroed weights keep 8 loads in
//     flight per wave even for avg-degree-17 tails (R5: serial remainder
//     handled ~half the edges -> VALUBusy 33%, latency-bound).

constexpr int D   = 128;
constexpr int BW  = 256;    // nodes per bucket (pow2)
constexpr int BSH = 8;      // log2(BW)
constexpr int CAP = 4608;   // per-bucket pair capacity (mean 4096 + 8 sigma)

__device__ __forceinline__ float lrelu(float x) { return x > 0.f ? x : 0.2f * x; }

// ---- fold: Wfd[h][k] = sum_c Wdst[k][h*16+c]*att_dst[h][c]; also zero gCnt ----
__global__ __launch_bounds__(128) void k_fold(const float* __restrict__ Wdst,
                                              const float* __restrict__ att_dst,
                                              float* __restrict__ Wfd,
                                              int* __restrict__ gCnt, int nb2) {
    int k = threadIdx.x;
    for (int i = k; i < nb2; i += 128) gCnt[i] = 0;
#pragma unroll
    for (int h = 0; h < 8; ++h) {
        float s = 0.f;
#pragma unroll
        for (int c = 0; c < 16; ++c)
            s += Wdst[k * 128 + h * 16 + c] * att_dst[h * 16 + c];
        Wfd[h * 128 + k] = s;
    }
}

// ---- phase 1: partition edges into buckets of packed 4B values.
//      4096-edge chunk per block -> ~21-entry bursts per (bucket,dir). ----
__global__ __launch_bounds__(256) void k_part(const int* __restrict__ src,
                                              const int* __restrict__ dst,
                                              int E_, int NB,
                                              int* __restrict__ gCnt,
                                              int* __restrict__ pairs) {
    __shared__ int cnt[512];
    __shared__ int basev[512];
    const int t = threadIdx.x;
    const int nb2 = 2 * NB;
    for (int i = t; i < nb2; i += 256) cnt[i] = 0;
    __syncthreads();
    const int base = blockIdx.x * 4096;
    int sv[16], dv[16];
    int m = 0;
#pragma unroll
    for (int i = 0; i < 16; ++i) {
        int e = base + i * 256 + t;
        if (e < E_) { sv[m] = src[e]; dv[m] = dst[e]; ++m; }
    }
    for (int i = 0; i < m; ++i) {
        atomicAdd(&cnt[dv[i] >> BSH], 1);
        atomicAdd(&cnt[NB + (sv[i] >> BSH)], 1);
    }
    __syncthreads();
    for (int i = t; i < nb2; i += 256) {
        int c = cnt[i];
        basev[i] = i * CAP + (c ? atomicAdd(&gCnt[i], c) : 0);
    }
    __syncthreads();
    for (int i = 0; i < m; ++i) {
        int d = dv[i], s = sv[i];
        int gbA = d >> BSH;
        int pA = atomicAdd(&basev[gbA], 1);
        if (pA < (gbA + 1) * CAP) pairs[pA] = ((d & (BW - 1)) << 16) | s;
        int gbB = NB + (s >> BSH);
        int pB = atomicAdd(&basev[gbB], 1);
        if (pB < (gbB + 1) * CAP) pairs[pB] = ((s & (BW - 1)) << 16) | d;
    }
}

// ---- phase 2: per (dir,bucket) counting sort -> rowst + eidx ----
__global__ __launch_bounds__(256) void k_build(const int* __restrict__ gCnt,
                                               const int* __restrict__ pairs,
                                               int N_, int NB, int RS, int EN,
                                               int* __restrict__ rowstBase,
                                               int* __restrict__ eidxBase) {
    const int t = threadIdx.x;
    const int bid = blockIdx.x;
    const int dir = (bid >= NB) ? 1 : 0;
    const int b = bid - dir * NB;
    int* rowst = rowstBase + (size_t)dir * RS;
    int* eidx  = eidxBase + (size_t)dir * EN;
    __shared__ int sc[256];
    __shared__ int cnt2[256];
    __shared__ int scan2[256];
    __shared__ int cursor[256];

    int c = (t < NB) ? min(gCnt[dir * NB + t], CAP) : 0;
    sc[t] = c;
    __syncthreads();
    for (int off = 1; off < 256; off <<= 1) {
        int v = (t >= off) ? sc[t - off] : 0;
        __syncthreads();
        sc[t] += v;
        __syncthreads();
    }
    const int count = min(gCnt[bid], CAP);
    const int nodeLo = b << BSH;
    const int nNodes = min(BW, N_ - nodeLo);
    const int segBase = nodeLo + sc[b] - count;

    cnt2[t] = (t < nNodes) ? 1 : 0;
    __syncthreads();
    const int pbase = bid * CAP;
    for (int j = t; j < count; j += 256)
        atomicAdd(&cnt2[pairs[pbase + j] >> 16], 1);
    __syncthreads();
    int mycnt = cnt2[t];
    scan2[t] = mycnt;
    __syncthreads();
    for (int off = 1; off < 256; off <<= 1) {
        int v = (t >= off) ? scan2[t - off] : 0;
        __syncthreads();
        scan2[t] += v;
        __syncthreads();
    }
    int startt = segBase + scan2[t] - mycnt;
    cursor[t] = startt;
    if (t < nNodes) rowst[nodeLo + t] = startt;
    if (b == NB - 1 && t == 0) rowst[N_] = segBase + count + nNodes;
    __syncthreads();
    if (t < nNodes) {
        int pos = atomicAdd(&cursor[t], 1);
        eidx[pos] = nodeLo + t;
    }
    for (int j = t; j < count; j += 256) {
        int v = pairs[pbase + j];
        int pos = atomicAdd(&cursor[v >> 16], 1);
        eidx[pos] = v & 0xFFFF;
    }
}

// ---- a_d standalone (fallback path only) ----
__global__ __launch_bounds__(256) void k_small8(const float* __restrict__ Xh,
                                                const float* __restrict__ Xt,
                                                const float* __restrict__ Wfd,
                                                float* __restrict__ aDh,
                                                float* __restrict__ aDt, int Nn) {
    int gid = blockIdx.x * 256 + threadIdx.x;
    int n = gid >> 3, h = gid & 7;
    if (n >= 2 * Nn) return;
    const float* X = (n < Nn) ? Xh : Xt;
    float* out = (n < Nn) ? aDh : aDt;
    int r = (n < Nn) ? n : n - Nn;
    const float4* xr = (const float4*)(X + (size_t)r * D);
    const float4* wr = (const float4*)(Wfd + h * D);
    float s = 0.f;
#pragma unroll 8
    for (int k4 = 0; k4 < 32; ++k4) {
        float4 xv = xr[k4], wv = wr[k4];
        s += fmaxf(xv.x, 0.f) * wv.x + fmaxf(xv.y, 0.f) * wv.y +
             fmaxf(xv.z, 0.f) * wv.z + fmaxf(xv.w, 0.f) * wv.w;
    }
    out[(size_t)r * 8 + h] = s;
}

// ---- GEMM: xs = relu(X)@W, a_s + a_d epilogues; two sides per dispatch ----
__global__ __launch_bounds__(256) void k_gemm(const float* __restrict__ X0,
                                              const float* __restrict__ X1,
                                              const float* __restrict__ W,
                                              const float* __restrict__ attS,
                                              const float* __restrict__ Wfd,
                                              float* __restrict__ Y0,
                                              float* __restrict__ Y1,
                                              float* __restrict__ aS0,
                                              float* __restrict__ aS1,
                                              float* __restrict__ aD0,
                                              float* __restrict__ aD1,
                                              int nrows, int blocksPerSide) {
    __shared__ float xls[64][132];    // +4 pad: aD epilogue rows spread banks
    const int t = threadIdx.x;
    const int side = (blockIdx.x >= blocksPerSide) ? 1 : 0;
    const float* X = side ? X1 : X0;
    float* Y  = side ? Y1 : Y0;
    float* aS = side ? aS1 : aS0;
    float* aD = side ? aD1 : aD0;
    const int bm = (blockIdx.x - side * blocksPerSide) * 64;
#pragma unroll
    for (int i = 0; i < 8; ++i) {
        int f = t + i * 256;
        int r = f >> 5, c4 = f & 31;
        int gr = bm + r;
        float4 v = make_float4(0.f, 0.f, 0.f, 0.f);
        if (gr < nrows) v = *(const float4*)(X + (size_t)gr * 128 + c4 * 4);
        v.x = fmaxf(v.x, 0.f); v.y = fmaxf(v.y, 0.f);
        v.z = fmaxf(v.z, 0.f); v.w = fmaxf(v.w, 0.f);
        *(float4*)&xls[r][c4 * 4] = v;
    }
    __syncthreads();
    const int q = t & 31;
    const int c0 = q * 4;
    const int r0 = (t >> 5) * 8;
    float acc[8][4];
#pragma unroll
    for (int r = 0; r < 8; ++r)
#pragma unroll
        for (int c = 0; c < 4; ++c) acc[r][c] = 0.f;

#pragma unroll 2
    for (int k = 0; k < 128; k += 4) {
        float4 wv[4];
#pragma unroll
        for (int i = 0; i < 4; ++i)
            wv[i] = *(const float4*)(W + (size_t)(k + i) * 128 + c0);
#pragma unroll
        for (int r = 0; r < 8; ++r) {
            float4 xv = *(const float4*)&xls[r0 + r][k];
            acc[r][0] = fmaf(xv.x, wv[0].x, acc[r][0]);
            acc[r][1] = fmaf(xv.x, wv[0].y, acc[r][1]);
            acc[r][2] = fmaf(xv.x, wv[0].z, acc[r][2]);
            acc[r][3] = fmaf(xv.x, wv[0].w, acc[r][3]);
            acc[r][0] = fmaf(xv.y, wv[1].x, acc[r][0]);
            acc[r][1] = fmaf(xv.y, wv[1].y, acc[r][1]);
            acc[r][2] = fmaf(xv.y, wv[1].z, acc[r][2]);
            acc[r][3] = fmaf(xv.y, wv[1].w, acc[r][3]);
            acc[r][0] = fmaf(xv.z, wv[2].x, acc[r][0]);
            acc[r][1] = fmaf(xv.z, wv[2].y, acc[r][1]);
            acc[r][2] = fmaf(xv.z, wv[2].z, acc[r][2]);
            acc[r][3] = fmaf(xv.z, wv[2].w, acc[r][3]);
            acc[r][0] = fmaf(xv.w, wv[3].x, acc[r][0]);
            acc[r][1] = fmaf(xv.w, wv[3].y, acc[r][1]);
            acc[r][2] = fmaf(xv.w, wv[3].z, acc[r][2]);
            acc[r][3] = fmaf(xv.w, wv[3].w, acc[r][3]);
        }
    }
    // a_s epilogue
    const int h = q >> 2;
    const float4 av = *(const float4*)(attS + h * 16 + (q & 3) * 4);
#pragma unroll
    for (int r = 0; r < 8; ++r) {
        int gr = bm + r0 + r;
        if (gr < nrows)
            *(float4*)(Y + (size_t)gr * 128 + c0) =
                make_float4(acc[r][0], acc[r][1], acc[r][2], acc[r][3]);
        float p = acc[r][0] * av.x + acc[r][1] * av.y + acc[r][2] * av.z + acc[r][3] * av.w;
        p += __shfl_xor(p, 1, 64);
        p += __shfl_xor(p, 2, 64);
        if ((q & 3) == 0 && gr < nrows) aS[(size_t)gr * 8 + h] = p;
    }
    // a_d epilogue: aD[bm+r][hh] = xls[r][:] . Wfd[hh][:]
#pragma unroll
    for (int o = t; o < 512; o += 256) {
        int r = o >> 3, hh = o & 7;
        const float4* wr = (const float4*)(Wfd + hh * 128);
        float s = 0.f;
#pragma unroll 8
        for (int k4 = 0; k4 < 32; ++k4) {
            float4 xv = *(const float4*)&xls[r][k4 * 4];
            float4 wv = wr[k4];
            s += xv.x * wv.x + xv.y * wv.y + xv.z * wv.z + xv.w * wv.w;
        }
        int gr = bm + r;
        if (gr < nrows) aD[(size_t)gr * 8 + hh] = s;
    }
}

// ---- aggregation: 1 wave/node, single-pass softmax, masked 4-chunk gather ----
__global__ __launch_bounds__(256) void k_agg(const float* __restrict__ xs0,
                                             const float* __restrict__ aS0,
                                             const float* __restrict__ aD0,
                                             const int* __restrict__ row0,
                                             const int* __restrict__ eix0,
                                             float* __restrict__ out0,
                                             const float* __restrict__ xs1,
                                             const float* __restrict__ aS1,
                                             const float* __restrict__ aD1,
                                             const int* __restrict__ row1,
                                             const int* __restrict__ eix1,
                                             float* __restrict__ out1,
                                             const float* __restrict__ bias,
                                             int Nn, int nWaves) {
    int w = (blockIdx.x * 256 + threadIdx.x) >> 6;
    if (w >= nWaves) return;
    const int dir = (w >= Nn) ? 1 : 0;
    const int d = w - dir * Nn;
    const float* xs = dir ? xs1 : xs0;
    const float* aS = dir ? aS1 : aS0;
    const float* aD = dir ? aD1 : aD0;
    const int* rowst = dir ? row1 : row0;
    const int* eidx  = dir ? eix1 : eix0;
    float* outp = dir ? out1 : out0;

    const int lane = threadIdx.x & 63;
    const int q = lane & 31;
    const int h = q >> 2;
    const int half = lane >> 5;
    const int start = rowst[d];
    const int end = rowst[d + 1];
    const int last = end - 1;
    const float ad = aD[(size_t)d * 8 + h];
    const float* xsq = xs + 4 * q;

    float4 acc = make_float4(0.f, 0.f, 0.f, 0.f);
    float den = 0.f;
    // masked chunks of 8 edges (4 per half): clamped indices, zeroed weights.
    for (int j = start + half; j < end; j += 8) {
        int i1 = j + 2, i2 = j + 4, i3 = j + 6;
        int s0 = eidx[j];
        int s1 = eidx[min(i1, last)];
        int s2 = eidx[min(i2, last)];
        int s3 = eidx[min(i3, last)];
        float a0 = aS[(size_t)s0 * 8 + h];
        float a1 = aS[(size_t)s1 * 8 + h];
        float a2 = aS[(size_t)s2 * 8 + h];
        float a3 = aS[(size_t)s3 * 8 + h];
        float4 x0 = *(const float4*)(xsq + (size_t)s0 * 128);
        float4 x1 = *(const float4*)(xsq + (size_t)s1 * 128);
        float4 x2 = *(const float4*)(xsq + (size_t)s2 * 128);
        float4 x3 = *(const float4*)(xsq + (size_t)s3 * 128);
        float w0 = __expf(lrelu(a0 + ad));
        float w1 = (i1 < end) ? __expf(lrelu(a1 + ad)) : 0.f;
        float w2 = (i2 < end) ? __expf(lrelu(a2 + ad)) : 0.f;
        float w3 = (i3 < end) ? __expf(lrelu(a3 + ad)) : 0.f;
        den += (w0 + w1) + (w2 + w3);
        acc.x = fmaf(w0, x0.x, acc.x); acc.y = fmaf(w0, x0.y, acc.y);
        acc.z = fmaf(w0, x0.z, acc.z); acc.w = fmaf(w0, x0.w, acc.w);
        acc.x = fmaf(w1, x1.x, acc.x); acc.y = fmaf(w1, x1.y, acc.y);
        acc.z = fmaf(w1, x1.z, acc.z); acc.w = fmaf(w1, x1.w, acc.w);
        acc.x = fmaf(w2, x2.x, acc.x); acc.y = fmaf(w2, x2.y, acc.y);
        acc.z = fmaf(w2, x2.z, acc.z); acc.w = fmaf(w2, x2.w, acc.w);
        acc.x = fmaf(w3, x3.x, acc.x); acc.y = fmaf(w3, x3.y, acc.y);
        acc.z = fmaf(w3, x3.z, acc.z); acc.w = fmaf(w3, x3.w, acc.w);
    }
    acc.x += __shfl_xor(acc.x, 32, 64);
    acc.y += __shfl_xor(acc.y, 32, 64);
    acc.z += __shfl_xor(acc.z, 32, 64);
    acc.w += __shfl_xor(acc.w, 32, 64);
    den   += __shfl_xor(den,   32, 64);
    if (half == 0) {
        float rden = 1.f / den;         // den > 0: self loop always present
        float4 bv = *(const float4*)(bias + 4 * q);
        *(float4*)(outp + (size_t)d * 128 + 4 * q) =
            make_float4(fmaf(acc.x, rden, bv.x), fmaf(acc.y, rden, bv.y),
                        fmaf(acc.z, rden, bv.z), fmaf(acc.w, rden, bv.w));
    }
}

extern "C" void kernel_launch(void* const* d_in, const int* in_sizes, int n_in,
                              void* d_out, int out_size, void* d_ws, size_t ws_size,
                              hipStream_t stream) {
    const float* x_h     = (const float*)d_in[0];
    const float* x_t     = (const float*)d_in[1];
    const int*   ei      = (const int*)d_in[2];
    const float* Wsrc    = (const float*)d_in[3];
    const float* Wdst    = (const float*)d_in[4];
    const float* att_src = (const float*)d_in[5];
    const float* att_dst = (const float*)d_in[6];
    const float* bias    = (const float*)d_in[7];

    const int N = in_sizes[0] / D;
    const int E = in_sizes[2] / 2;
    const int* src = ei;
    const int* dst = ei + E;
    const int NB = (N + BW - 1) >> BSH;
    const int RS = N + 8;
    const int EN = E + N;
    const int gemmGrid = (N + 63) / 64;

    auto align256 = [](size_t b) { return (b + 255) & ~(size_t)255; };
    const size_t szWfd  = align256(8 * 128 * sizeof(float));
    const size_t szA    = align256((size_t)N * 8 * sizeof(float));
    const size_t szXs   = align256((size_t)N * 128 * sizeof(float));
    const size_t szCnt  = align256((size_t)2 * NB * sizeof(int));
    const size_t szRow  = align256((size_t)2 * RS * sizeof(int));
    const size_t szEidx = align256((size_t)2 * EN * sizeof(int));
    const size_t needBig = szWfd + 4 * szA + 2 * szXs + szCnt + szRow + szEidx;

    char* p = (char*)d_ws;
    auto alloc = [&](size_t bytes) { char* q = p; p += align256(bytes); return q; };

    float* out_h = (float*)d_out;
    float* out_t = (float*)d_out + (size_t)N * 128;

    if (ws_size >= needBig) {
        // ---- big path: both sides/dirs merged ----
        float* Wfd  = (float*)alloc(8 * 128 * sizeof(float));
        float* aS_h = (float*)alloc((size_t)N * 8 * sizeof(float));
        float* aS_t = (float*)alloc((size_t)N * 8 * sizeof(float));
        float* aD_h = (float*)alloc((size_t)N * 8 * sizeof(float));
        float* aD_t = (float*)alloc((size_t)N * 8 * sizeof(float));
        float* xs_h = (float*)alloc((size_t)N * 128 * sizeof(float));
        float* xs_t = (float*)alloc((size_t)N * 128 * sizeof(float));
        int*   gCnt  = (int*)alloc((size_t)2 * NB * sizeof(int));
        int*   rowst = (int*)alloc((size_t)2 * RS * sizeof(int));
        int*   eidx  = (int*)alloc((size_t)2 * EN * sizeof(int));
        int* pairs = (int*)xs_h;   // 7.2MB, dead before k_gemm writes xs_h

        k_fold<<<1, 128, 0, stream>>>(Wdst, att_dst, Wfd, gCnt, 2 * NB);
        k_part<<<(E + 4095) / 4096, 256, 0, stream>>>(src, dst, E, NB, gCnt, pairs);
        k_build<<<2 * NB, 256, 0, stream>>>(gCnt, pairs, N, NB, RS, EN, rowst, eidx);
        k_gemm<<<2 * gemmGrid, 256, 0, stream>>>(x_h, x_t, Wsrc, att_src, Wfd,
                                                 xs_h, xs_t, aS_h, aS_t, aD_h, aD_t,
                                                 N, gemmGrid);
        // dir0: t_rep = GAT(h->t): xs_h/aS_h, aD_t, segments dst -> out_t
        // dir1: h_rep = GAT(t->h): xs_t/aS_t, aD_h, segments src -> out_h
        k_agg<<<(2 * N + 3) / 4, 256, 0, stream>>>(
            xs_h, aS_h, aD_t, rowst, eidx, out_t,
            xs_t, aS_t, aD_h, rowst + RS, eidx + EN, out_h,
            bias, N, 2 * N);
    } else {
        // ---- fallback: single xs buffer, sequential directions ----
        float* Wfd  = (float*)alloc(8 * 128 * sizeof(float));
        float* aS   = (float*)alloc((size_t)N * 8 * sizeof(float));
        float* aD_h = (float*)alloc((size_t)N * 8 * sizeof(float));
        float* aD_t = (float*)alloc((size_t)N * 8 * sizeof(float));
        float* xs   = (float*)alloc((size_t)N * 128 * sizeof(float));
        int*   gCnt  = (int*)alloc((size_t)2 * NB * sizeof(int));
        int*   rowst = (int*)alloc((size_t)2 * RS * sizeof(int));
        int*   eidx  = (int*)alloc((size_t)2 * EN * sizeof(int));
        int* pairs = (int*)xs;

        k_fold<<<1, 128, 0, stream>>>(Wdst, att_dst, Wfd, gCnt, 2 * NB);
        k_part<<<(E + 4095) / 4096, 256, 0, stream>>>(src, dst, E, NB, gCnt, pairs);
        k_build<<<2 * NB, 256, 0, stream>>>(gCnt, pairs, N, NB, RS, EN, rowst, eidx);
        k_small8<<<(16 * N + 255) / 256, 256, 0, stream>>>(x_h, x_t, Wfd, aD_h, aD_t, N);

        k_gemm<<<gemmGrid, 256, 0, stream>>>(x_h, x_h, Wsrc, att_src, Wfd,
                                             xs, xs, aS, aS, aD_h, aD_h, N, gemmGrid);
        k_agg<<<(N + 3) / 4, 256, 0, stream>>>(
            xs, aS, aD_t, rowst, eidx, out_t,
            xs, aS, aD_t, rowst, eidx, out_t, bias, N, N);
        k_gemm<<<gemmGrid, 256, 0, stream>>>(x_t, x_t, Wsrc, att_src, Wfd,
                                             xs, xs, aS, aS, aD_t, aD_t, N, gemmGrid);
        k_agg<<<(N + 3) / 4, 256, 0, stream>>>(
            xs, aS, aD_h, rowst + RS, eidx + EN, out_h,
            xs, aS, aD_h, rowst + RS, eidx + EN, out_h, bias, N, N);
    }
}

// Round 7
// 260.350 us; speedup vs baseline: 1.3775x; 1.3775x over previous
//
#include <hip/hip_runtime.h>
#include <hip/hip_fp16.h>

// Bipartite GATConv forward (both directions), fp32 in/out, fp16 internals.
//   - CSR build: bucketed 2-phase (k_part -> k_build), single-writer lines
//     (R4-confirmed fix for cross-XCD partial-line write amplification).
//   - k_prep: WhT[144][128] fp16 = W_src^T (rows 0..127) ++ att_src-folded
//     W_src (rows 128..135) ++ att_dst-folded W_dst (rows 136..143).
//   - k_gemm: MFMA fp16 (v_mfma_f32_16x16x32_f16, fp32 accum). A-frag = 8
//     consecutive k per lane (m97-verified), C/D col=lane&15,row=(l>>4)*4+j
//     (m89-verified). 9th N-tile emits a_s (cols 0..7) and a_d (cols 8..15)
//     directly -- no shuffle epilogue. xs stored fp16 (halves k_agg traffic,
//     25.6MB working set ~ L2-resident).
//   - k_agg: single-pass softmax (exact, exp(-max) cancels; logits max ~9.5
//     << 88), half-wave-per-edge 8B fp16 gathers, masked 4-chunk loop.

constexpr int D   = 128;
constexpr int BW  = 256;    // nodes per bucket (pow2)
constexpr int BSH = 8;      // log2(BW)
constexpr int CAP = 4608;   // per-bucket pair capacity (mean 4096 + 8 sigma)

typedef _Float16 f16x8 __attribute__((ext_vector_type(8)));
typedef _Float16 f16x4 __attribute__((ext_vector_type(4)));
typedef float    f32x4 __attribute__((ext_vector_type(4)));

__device__ __forceinline__ float lrelu(float x) { return x > 0.f ? x : 0.2f * x; }

// ---- prep: WhT fp16 [144][128]; also zero gCnt ----
__global__ __launch_bounds__(128) void k_prep(const float* __restrict__ Wsrc,
                                              const float* __restrict__ Wdst,
                                              const float* __restrict__ att_src,
                                              const float* __restrict__ att_dst,
                                              _Float16* __restrict__ WhT,
                                              int* __restrict__ gCnt, int nb2) {
    const int n = blockIdx.x, k = threadIdx.x;
    if (n == 0)
        for (int i = k; i < nb2; i += 128) gCnt[i] = 0;
    float v;
    if (n < 128) {
        v = Wsrc[k * 128 + n];
    } else if (n < 136) {
        int h = n - 128;
        float s = 0.f;
#pragma unroll
        for (int c = 0; c < 16; ++c) s += Wsrc[k * 128 + h * 16 + c] * att_src[h * 16 + c];
        v = s;
    } else {
        int h = n - 136;
        float s = 0.f;
#pragma unroll
        for (int c = 0; c < 16; ++c) s += Wdst[k * 128 + h * 16 + c] * att_dst[h * 16 + c];
        v = s;
    }
    WhT[(size_t)n * 128 + k] = (_Float16)v;
}

// ---- phase 1: partition edges into buckets of packed 4B values ----
__global__ __launch_bounds__(256) void k_part(const int* __restrict__ src,
                                              const int* __restrict__ dst,
                                              int E_, int NB,
                                              int* __restrict__ gCnt,
                                              int* __restrict__ pairs) {
    __shared__ int cnt[512];
    __shared__ int basev[512];
    const int t = threadIdx.x;
    const int nb2 = 2 * NB;
    for (int i = t; i < nb2; i += 256) cnt[i] = 0;
    __syncthreads();
    const int base = blockIdx.x * 4096;
    int sv[16], dv[16];
    int m = 0;
#pragma unroll
    for (int i = 0; i < 16; ++i) {
        int e = base + i * 256 + t;
        if (e < E_) { sv[m] = src[e]; dv[m] = dst[e]; ++m; }
    }
    for (int i = 0; i < m; ++i) {
        atomicAdd(&cnt[dv[i] >> BSH], 1);
        atomicAdd(&cnt[NB + (sv[i] >> BSH)], 1);
    }
    __syncthreads();
    for (int i = t; i < nb2; i += 256) {
        int c = cnt[i];
        basev[i] = i * CAP + (c ? atomicAdd(&gCnt[i], c) : 0);
    }
    __syncthreads();
    for (int i = 0; i < m; ++i) {
        int d = dv[i], s = sv[i];
        int gbA = d >> BSH;
        int pA = atomicAdd(&basev[gbA], 1);
        if (pA < (gbA + 1) * CAP) pairs[pA] = ((d & (BW - 1)) << 16) | s;
        int gbB = NB + (s >> BSH);
        int pB = atomicAdd(&basev[gbB], 1);
        if (pB < (gbB + 1) * CAP) pairs[pB] = ((s & (BW - 1)) << 16) | d;
    }
}

// ---- phase 2: per (dir,bucket) counting sort -> rowst + eidx ----
__global__ __launch_bounds__(256) void k_build(const int* __restrict__ gCnt,
                                               const int* __restrict__ pairs,
                                               int N_, int NB, int RS, int EN,
                                               int* __restrict__ rowstBase,
                                               int* __restrict__ eidxBase) {
    const int t = threadIdx.x;
    const int bid = blockIdx.x;
    const int dir = (bid >= NB) ? 1 : 0;
    const int b = bid - dir * NB;
    int* rowst = rowstBase + (size_t)dir * RS;
    int* eidx  = eidxBase + (size_t)dir * EN;
    __shared__ int sc[256];
    __shared__ int cnt2[256];
    __shared__ int scan2[256];
    __shared__ int cursor[256];

    int c = (t < NB) ? min(gCnt[dir * NB + t], CAP) : 0;
    sc[t] = c;
    __syncthreads();
    for (int off = 1; off < 256; off <<= 1) {
        int v = (t >= off) ? sc[t - off] : 0;
        __syncthreads();
        sc[t] += v;
        __syncthreads();
    }
    const int count = min(gCnt[bid], CAP);
    const int nodeLo = b << BSH;
    const int nNodes = min(BW, N_ - nodeLo);
    const int segBase = nodeLo + sc[b] - count;

    cnt2[t] = (t < nNodes) ? 1 : 0;
    __syncthreads();
    const int pbase = bid * CAP;
    for (int j = t; j < count; j += 256)
        atomicAdd(&cnt2[pairs[pbase + j] >> 16], 1);
    __syncthreads();
    int mycnt = cnt2[t];
    scan2[t] = mycnt;
    __syncthreads();
    for (int off = 1; off < 256; off <<= 1) {
        int v = (t >= off) ? scan2[t - off] : 0;
        __syncthreads();
        scan2[t] += v;
        __syncthreads();
    }
    int startt = segBase + scan2[t] - mycnt;
    cursor[t] = startt;
    if (t < nNodes) rowst[nodeLo + t] = startt;
    if (b == NB - 1 && t == 0) rowst[N_] = segBase + count + nNodes;
    __syncthreads();
    if (t < nNodes) {
        int pos = atomicAdd(&cursor[t], 1);
        eidx[pos] = nodeLo + t;
    }
    for (int j = t; j < count; j += 256) {
        int v = pairs[pbase + j];
        int pos = atomicAdd(&cursor[v >> 16], 1);
        eidx[pos] = v & 0xFFFF;
    }
}

// ---- MFMA GEMM: xs(fp16) = relu(X)@W; aSD[n][0..7]=a_s, [8..15]=a_d ----
__global__ __launch_bounds__(256) void k_gemm(const float* __restrict__ X0,
                                              const float* __restrict__ X1,
                                              const _Float16* __restrict__ WhT,
                                              _Float16* __restrict__ Y0,
                                              _Float16* __restrict__ Y1,
                                              float* __restrict__ aSD0,
                                              float* __restrict__ aSD1,
                                              int nrows, int blocksPerSide) {
    const int t = threadIdx.x;
    const int side = (blockIdx.x >= blocksPerSide) ? 1 : 0;
    const float* X = side ? X1 : X0;
    _Float16* Y = side ? Y1 : Y0;
    float* aSD  = side ? aSD1 : aSD0;
    const int bm = (blockIdx.x - side * blocksPerSide) * 64;
    const int wid = t >> 6, lane = t & 63;
    const int m = lane & 15, g = lane >> 4;
    const int m0 = bm + wid * 16;
    const int arow = m0 + m;
    const bool rv = arow < nrows;
    const float* xr = X + (size_t)arow * 128;

    // A-frags: lane holds 8 consecutive k at row (lane&15); k0 = kc*32 + g*8
    f16x8 af[4];
#pragma unroll
    for (int kc = 0; kc < 4; ++kc) {
        int k0 = kc * 32 + g * 8;
        float4 u0 = rv ? *(const float4*)(xr + k0)     : make_float4(0.f, 0.f, 0.f, 0.f);
        float4 u1 = rv ? *(const float4*)(xr + k0 + 4) : make_float4(0.f, 0.f, 0.f, 0.f);
        f16x8 a;
        a[0] = (_Float16)fmaxf(u0.x, 0.f); a[1] = (_Float16)fmaxf(u0.y, 0.f);
        a[2] = (_Float16)fmaxf(u0.z, 0.f); a[3] = (_Float16)fmaxf(u0.w, 0.f);
        a[4] = (_Float16)fmaxf(u1.x, 0.f); a[5] = (_Float16)fmaxf(u1.y, 0.f);
        a[6] = (_Float16)fmaxf(u1.z, 0.f); a[7] = (_Float16)fmaxf(u1.w, 0.f);
        af[kc] = a;
    }
    f32x4 acc[9];
#pragma unroll
    for (int i = 0; i < 9; ++i) acc[i] = (f32x4){0.f, 0.f, 0.f, 0.f};
#pragma unroll
    for (int nt = 0; nt < 9; ++nt) {
        const _Float16* wb = WhT + (size_t)(nt * 16 + m) * 128 + g * 8;
#pragma unroll
        for (int kc = 0; kc < 4; ++kc) {
            f16x8 b = *(const f16x8*)(wb + kc * 32);
            acc[nt] = __builtin_amdgcn_mfma_f32_16x16x32_f16(af[kc], b, acc[nt], 0, 0, 0);
        }
    }
    // xs store (fp16): C/D layout col=lane&15, row=(lane>>4)*4+j
#pragma unroll
    for (int nt = 0; nt < 8; ++nt) {
#pragma unroll
        for (int j = 0; j < 4; ++j) {
            int r = m0 + g * 4 + j;
            if (r < nrows) Y[(size_t)r * 128 + nt * 16 + m] = (_Float16)acc[nt][j];
        }
    }
    // a_s / a_d from the 9th tile: cols 0..7 = a_s, 8..15 = a_d
#pragma unroll
    for (int j = 0; j < 4; ++j) {
        int r = m0 + g * 4 + j;
        if (r < nrows) aSD[(size_t)r * 16 + m] = acc[8][j];
    }
}

__device__ __forceinline__ float4 ldx4(const _Float16* p) {
    f16x4 v = *(const f16x4*)p;
    return make_float4((float)v[0], (float)v[1], (float)v[2], (float)v[3]);
}

// ---- aggregation: 1 wave/node, single-pass softmax, masked 4-chunk gather.
//      aS read from aSD_src[s*16 + h]; aD from aSD_dst[d*16 + 8 + h]. ----
__global__ __launch_bounds__(256) void k_agg(const _Float16* __restrict__ xs0,
                                             const float* __restrict__ aS0,
                                             const float* __restrict__ aD0,
                                             const int* __restrict__ row0,
                                             const int* __restrict__ eix0,
                                             float* __restrict__ out0,
                                             const _Float16* __restrict__ xs1,
                                             const float* __restrict__ aS1,
                                             const float* __restrict__ aD1,
                                             const int* __restrict__ row1,
                                             const int* __restrict__ eix1,
                                             float* __restrict__ out1,
                                             const float* __restrict__ bias,
                                             int Nn, int nWaves) {
    int w = (blockIdx.x * 256 + threadIdx.x) >> 6;
    if (w >= nWaves) return;
    const int dir = (w >= Nn) ? 1 : 0;
    const int d = w - dir * Nn;
    const _Float16* xs = dir ? xs1 : xs0;
    const float* aS = dir ? aS1 : aS0;     // stride-16 rows
    const float* aD = dir ? aD1 : aD0;     // stride-16 rows, pre-offset +8
    const int* rowst = dir ? row1 : row0;
    const int* eidx  = dir ? eix1 : eix0;
    float* outp = dir ? out1 : out0;

    const int lane = threadIdx.x & 63;
    const int q = lane & 31;
    const int h = q >> 2;
    const int half = lane >> 5;
    const int start = rowst[d];
    const int end = rowst[d + 1];
    const int last = end - 1;
    const float ad = aD[(size_t)d * 16 + h];
    const _Float16* xsq = xs + 4 * q;

    float4 acc = make_float4(0.f, 0.f, 0.f, 0.f);
    float den = 0.f;
    for (int j = start + half; j < end; j += 8) {
        int i1 = j + 2, i2 = j + 4, i3 = j + 6;
        int s0 = eidx[j];
        int s1 = eidx[min(i1, last)];
        int s2 = eidx[min(i2, last)];
        int s3 = eidx[min(i3, last)];
        float a0 = aS[(size_t)s0 * 16 + h];
        float a1 = aS[(size_t)s1 * 16 + h];
        float a2 = aS[(size_t)s2 * 16 + h];
        float a3 = aS[(size_t)s3 * 16 + h];
        float4 x0 = ldx4(xsq + (size_t)s0 * 128);
        float4 x1 = ldx4(xsq + (size_t)s1 * 128);
        float4 x2 = ldx4(xsq + (size_t)s2 * 128);
        float4 x3 = ldx4(xsq + (size_t)s3 * 128);
        float w0 = __expf(lrelu(a0 + ad));
        float w1 = (i1 < end) ? __expf(lrelu(a1 + ad)) : 0.f;
        float w2 = (i2 < end) ? __expf(lrelu(a2 + ad)) : 0.f;
        float w3 = (i3 < end) ? __expf(lrelu(a3 + ad)) : 0.f;
        den += (w0 + w1) + (w2 + w3);
        acc.x = fmaf(w0, x0.x, acc.x); acc.y = fmaf(w0, x0.y, acc.y);
        acc.z = fmaf(w0, x0.z, acc.z); acc.w = fmaf(w0, x0.w, acc.w);
        acc.x = fmaf(w1, x1.x, acc.x); acc.y = fmaf(w1, x1.y, acc.y);
        acc.z = fmaf(w1, x1.z, acc.z); acc.w = fmaf(w1, x1.w, acc.w);
        acc.x = fmaf(w2, x2.x, acc.x); acc.y = fmaf(w2, x2.y, acc.y);
        acc.z = fmaf(w2, x2.z, acc.z); acc.w = fmaf(w2, x2.w, acc.w);
        acc.x = fmaf(w3, x3.x, acc.x); acc.y = fmaf(w3, x3.y, acc.y);
        acc.z = fmaf(w3, x3.z, acc.z); acc.w = fmaf(w3, x3.w, acc.w);
    }
    acc.x += __shfl_xor(acc.x, 32, 64);
    acc.y += __shfl_xor(acc.y, 32, 64);
    acc.z += __shfl_xor(acc.z, 32, 64);
    acc.w += __shfl_xor(acc.w, 32, 64);
    den   += __shfl_xor(den,   32, 64);
    if (half == 0) {
        float rden = 1.f / den;         // den > 0: self loop always present
        float4 bv = *(const float4*)(bias + 4 * q);
        *(float4*)(outp + (size_t)d * 128 + 4 * q) =
            make_float4(fmaf(acc.x, rden, bv.x), fmaf(acc.y, rden, bv.y),
                        fmaf(acc.z, rden, bv.z), fmaf(acc.w, rden, bv.w));
    }
}

extern "C" void kernel_launch(void* const* d_in, const int* in_sizes, int n_in,
                              void* d_out, int out_size, void* d_ws, size_t ws_size,
                              hipStream_t stream) {
    const float* x_h     = (const float*)d_in[0];
    const float* x_t     = (const float*)d_in[1];
    const int*   ei      = (const int*)d_in[2];
    const float* Wsrc    = (const float*)d_in[3];
    const float* Wdst    = (const float*)d_in[4];
    const float* att_src = (const float*)d_in[5];
    const float* att_dst = (const float*)d_in[6];
    const float* bias    = (const float*)d_in[7];

    const int N = in_sizes[0] / D;
    const int E = in_sizes[2] / 2;
    const int* src = ei;
    const int* dst = ei + E;
    const int NB = (N + BW - 1) >> BSH;
    const int RS = N + 8;
    const int EN = E + N;
    const int gemmGrid = (N + 63) / 64;

    char* p = (char*)d_ws;
    auto alloc = [&](size_t bytes) {
        char* q = p;
        p += (bytes + 255) & ~(size_t)255;
        return q;
    };
    _Float16* WhT   = (_Float16*)alloc((size_t)144 * 128 * sizeof(_Float16));
    float*    aSD_h = (float*)alloc((size_t)N * 16 * sizeof(float));
    float*    aSD_t = (float*)alloc((size_t)N * 16 * sizeof(float));
    _Float16* xs_h  = (_Float16*)alloc((size_t)N * 128 * sizeof(_Float16));
    _Float16* xs_t  = (_Float16*)alloc((size_t)N * 128 * sizeof(_Float16));
    int* gCnt  = (int*)alloc((size_t)2 * NB * sizeof(int));
    int* rowst = (int*)alloc((size_t)2 * RS * sizeof(int));
    int* eidx  = (int*)alloc((size_t)2 * EN * sizeof(int));
    (void)ws_size;
    int* pairs = (int*)xs_h;   // 7.2MB <= 12.8MB, dead before k_gemm writes xs_h

    float* out_h = (float*)d_out;
    float* out_t = (float*)d_out + (size_t)N * 128;

    k_prep<<<144, 128, 0, stream>>>(Wsrc, Wdst, att_src, att_dst, WhT, gCnt, 2 * NB);
    k_part<<<(E + 4095) / 4096, 256, 0, stream>>>(src, dst, E, NB, gCnt, pairs);
    k_build<<<2 * NB, 256, 0, stream>>>(gCnt, pairs, N, NB, RS, EN, rowst, eidx);
    k_gemm<<<2 * gemmGrid, 256, 0, stream>>>(x_h, x_t, WhT, xs_h, xs_t,
                                             aSD_h, aSD_t, N, gemmGrid);
    // dir0: t_rep = GAT(h->t): xs_h, a_s from h-side, a_d from t-side, seg=dst
    // dir1: h_rep = GAT(t->h): xs_t, a_s from t-side, a_d from h-side, seg=src
    k_agg<<<(2 * N + 3) / 4, 256, 0, stream>>>(
        xs_h, aSD_h, aSD_t + 8, rowst, eidx, out_t,
        xs_t, aSD_t, aSD_h + 8, rowst + RS, eidx + EN, out_h,
        bias, N, 2 * N);
}